// Round 3
// baseline (3477.427 us; speedup 1.0000x reference)
//
#include <hip/hip_runtime.h>

typedef unsigned int u32;

#define D 128

__device__ inline u32 fkey(float f) {
    u32 u = __float_as_uint(f);
    return (u & 0x80000000u) ? ~u : (u | 0x80000000u);
}
__device__ inline float fdec(u32 u) {
    return (u & 0x80000000u) ? __uint_as_float(u & 0x7fffffffu) : __uint_as_float(~u);
}

// ---------------- init (before precompute): ssum, cnt, key ----------------
__global__ void k_init(float* ssum, float* cnt, u32* key, int N) {
    int i = blockIdx.x * blockDim.x + threadIdx.x;
    if (i < N) { ssum[i] = 0.f; cnt[i] = 0.f; key[i] = 0x80000000u; }  // key(0.0)
}

// ------- init2 (after k_edge_logit): zero agg region (aliases A) ----------
__global__ void k_init2(float* agg, int N) {
    int i = blockIdx.x * blockDim.x + threadIdx.x;
    if (i < N * 256) agg[i] = 0.f;
}

// --- A = emb @ Wcat^T  (A[n][d<128]=W_r@emb[n], A[n][128+d]=W_h@emb[n]) ---
__global__ __launch_bounds__(256) void k_precompute(const float* __restrict__ emb,
                                                    const float* __restrict__ Wattn,
                                                    float* __restrict__ A, int N) {
    __shared__ float semb[8][D];
    int nb = blockIdx.x * 8;
    int tid = threadIdx.x;
    for (int i = tid; i < 8 * D; i += 256) {
        int n = nb + (i >> 7);
        semb[i >> 7][i & 127] = (n < N) ? emb[(size_t)n * D + (i & 127)] : 0.f;
    }
    __syncthreads();
    int d = tid;  // 0..255
    const float* wrow = (d < D) ? (Wattn + (size_t)d * 256)
                                : (Wattn + (size_t)(d - 128) * 256 + 128);
    float acc[8];
#pragma unroll
    for (int n = 0; n < 8; n++) acc[n] = 0.f;
    for (int k = 0; k < D; k += 4) {
        float4 w = *(const float4*)(wrow + k);
#pragma unroll
        for (int n = 0; n < 8; n++) {
            acc[n] += w.x * semb[n][k] + w.y * semb[n][k + 1] +
                      w.z * semb[n][k + 2] + w.w * semb[n][k + 3];
        }
    }
#pragma unroll
    for (int n = 0; n < 8; n++) {
        int nn = nb + n;
        if (nn < N) A[(size_t)nn * 256 + d] = acc[n];
    }
}

// ---------------- per-edge logit + segment max ----------------
__global__ __launch_bounds__(256) void k_edge_logit(const float* __restrict__ A,
                                                    const int* __restrict__ src_a,
                                                    const int* __restrict__ dst_a,
                                                    const float* __restrict__ Wb,
                                                    const float* __restrict__ w0w,
                                                    const float* __restrict__ w0b,
                                                    float* __restrict__ e_buf,
                                                    u32* __restrict__ key, int E) {
    int e = blockIdx.x * 4 + (threadIdx.x >> 6);
    if (e >= E) return;
    int lane = threadIdx.x & 63;
    int src = src_a[e], dst = dst_a[e];
    float2 r2 = *(const float2*)(A + (size_t)dst * 256 + 2 * lane);
    float2 h2 = *(const float2*)(A + (size_t)src * 256 + 128 + 2 * lane);
    float2 b2 = *(const float2*)(Wb + 2 * lane);
    float2 w2 = *(const float2*)(w0w + 2 * lane);
    float p = tanhf(r2.x + h2.x + b2.x) * w2.x + tanhf(r2.y + h2.y + b2.y) * w2.y;
#pragma unroll
    for (int off = 32; off; off >>= 1) p += __shfl_down(p, off);
    if (lane == 0) {
        float v = p + w0b[0];
        e_buf[e] = v;
        atomicMax(key + src, fkey(v));
    }
}

// ---------------- exp + segment sum ----------------
__global__ void k_exp(const int* __restrict__ src_a, float* __restrict__ e_buf,
                      const u32* __restrict__ key, float* __restrict__ ssum, int E) {
    int e = blockIdx.x * blockDim.x + threadIdx.x;
    if (e >= E) return;
    int src = src_a[e];
    float ev = __expf(e_buf[e] - fdec(key[src]));
    e_buf[e] = ev;
    atomicAdd(ssum + src, ev);
}

// ---------------- attention-weighted scatter ----------------
__global__ __launch_bounds__(256) void k_attn_agg(const float* __restrict__ emb,
                                                  const int* __restrict__ src_a,
                                                  const int* __restrict__ dst_a,
                                                  const float* __restrict__ e_buf,
                                                  const float* __restrict__ ssum,
                                                  float* __restrict__ attn_agg, int E) {
    long long idx = (long long)blockIdx.x * blockDim.x + threadIdx.x;
    int e = (int)(idx >> 6);
    if (e >= E) return;
    int p = (int)(idx & 63);
    int src = src_a[e], dst = dst_a[e];
    float a = e_buf[e] / (ssum[src] + 1e-9f);
    float2 v = *(const float2*)(emb + (size_t)dst * D + 2 * p);
    float* base = attn_agg + (size_t)src * D + 2 * p;
    atomicAdd(base, a * v.x);
    atomicAdd(base + 1, a * v.y);
}

// ---------------- mean aggregation scatter (er/ee/rr) ----------------
// mode 0: weight 1 (er, rr); mode 1: weight w[e] (ee)
__global__ __launch_bounds__(256) void k_mean(const float* __restrict__ emb,
                                              const int* __restrict__ gat,
                                              const int* __restrict__ sct,
                                              const float* __restrict__ w,
                                              float* __restrict__ mean_agg,
                                              float* __restrict__ cnt, int E, int mode) {
    long long idx = (long long)blockIdx.x * blockDim.x + threadIdx.x;
    int e = (int)(idx >> 6);
    if (e >= E) return;
    int p = (int)(idx & 63);
    int g = gat[e], s = sct[e];
    float wt = (mode == 1) ? w[e] : 1.f;
    float2 v = *(const float2*)(emb + (size_t)g * D + 2 * p);
    float* base = mean_agg + (size_t)s * D + 2 * p;
    atomicAdd(base, wt * v.x);
    atomicAdd(base + 1, wt * v.y);
    if (p == 0) atomicAdd(cnt + s, wt);
}

// ---------------- fused epilogue: 3 matvecs + tanh + sum ----------------
__global__ __launch_bounds__(256) void k_final(const float* __restrict__ emb,
                                               const float* __restrict__ attn_agg,
                                               const float* __restrict__ mean_agg,
                                               const float* __restrict__ cnt,
                                               const float* __restrict__ W1, const float* __restrict__ b1,
                                               const float* __restrict__ W2, const float* __restrict__ b2,
                                               const float* __restrict__ W3, const float* __restrict__ b3,
                                               float* __restrict__ out, int N) {
    __shared__ float s_e[16][D];
    __shared__ float s_a[16][D];
    __shared__ float s_m[16][D];
    int nb = blockIdx.x * 16;
    int tid = threadIdx.x;
    for (int i = tid; i < 16 * D; i += 256) {
        int n = nb + (i >> 7);
        int d = i & 127;
        int r = i >> 7;
        if (n < N) {
            s_e[r][d] = emb[(size_t)n * D + d];
            s_a[r][d] = attn_agg[(size_t)n * D + d];
            float c = cnt[n];
            c = c > 1.f ? c : 1.f;
            s_m[r][d] = mean_agg[(size_t)n * D + d] / c;
        } else {
            s_e[r][d] = 0.f; s_a[r][d] = 0.f; s_m[r][d] = 0.f;
        }
    }
    __syncthreads();
    int d = tid & 127;
    int half = tid >> 7;  // 0 or 1
    const float* w1r = W1 + (size_t)d * D;
    const float* w2r = W2 + (size_t)d * D;
    const float* w3r = W3 + (size_t)d * D;
    float acc1[8], acc2[8], acc3[8];
#pragma unroll
    for (int n = 0; n < 8; n++) { acc1[n] = 0.f; acc2[n] = 0.f; acc3[n] = 0.f; }
    for (int k = 0; k < D; k += 4) {
        float4 w1 = *(const float4*)(w1r + k);
        float4 w2 = *(const float4*)(w2r + k);
        float4 w3 = *(const float4*)(w3r + k);
#pragma unroll
        for (int n = 0; n < 8; n++) {
            int nn = 2 * n + half;
            const float* pe = &s_e[nn][k];
            const float* pa = &s_a[nn][k];
            const float* pm = &s_m[nn][k];
            acc1[n] += w1.x * pe[0] + w1.y * pe[1] + w1.z * pe[2] + w1.w * pe[3];
            acc2[n] += w2.x * pa[0] + w2.y * pa[1] + w2.z * pa[2] + w2.w * pa[3];
            acc3[n] += w3.x * pm[0] + w3.y * pm[1] + w3.z * pm[2] + w3.w * pm[3];
        }
    }
    float bb1 = b1[d], bb2 = b2[d], bb3 = b3[d];
#pragma unroll
    for (int n = 0; n < 8; n++) {
        int gn = nb + 2 * n + half;
        if (gn < N)
            out[(size_t)gn * D + d] =
                tanhf(acc1[n] + bb1) + tanhf(acc2[n] + bb2) + tanhf(acc3[n] + bb3);
    }
}

extern "C" void kernel_launch(void* const* d_in, const int* in_sizes, int n_in,
                              void* d_out, int out_size, void* d_ws, size_t ws_size,
                              hipStream_t stream) {
    const float* emb     = (const float*)d_in[0];
    const int*   er_src  = (const int*)d_in[1];
    const int*   er_dst  = (const int*)d_in[2];
    const int*   ee_src  = (const int*)d_in[3];
    const int*   ee_dst  = (const int*)d_in[4];
    const float* ee_w    = (const float*)d_in[5];
    const int*   rr_src  = (const int*)d_in[6];
    const int*   rr_dst  = (const int*)d_in[7];
    const float* Wattn   = (const float*)d_in[8];
    const float* Wattn_b = (const float*)d_in[9];
    const float* w0w     = (const float*)d_in[10];
    const float* w0b     = (const float*)d_in[11];
    const float* W1      = (const float*)d_in[12];
    const float* b1      = (const float*)d_in[13];
    const float* W2      = (const float*)d_in[14];
    const float* b2      = (const float*)d_in[15];
    const float* W3      = (const float*)d_in[16];
    const float* b3      = (const float*)d_in[17];
    float* out = (float*)d_out;

    int N    = in_sizes[0] / D;
    int E_ER = in_sizes[1];
    int E_EE = in_sizes[3];
    int E_RR = in_sizes[6];

    char* ws = (char*)d_ws;
    size_t off = 0;
    auto alloc = [&](size_t bytes) -> void* {
        void* p = ws + off;
        off += (bytes + 255) & ~(size_t)255;
        return p;
    };
    // A (N x 256 f32) exactly aliases [attn_agg | mean_agg] (N x 128 f32 each);
    // lifetimes disjoint: A dead after k_edge_logit, aggs zeroed after.
    // Total ws ~= 102.4 + 3.2 + 1.2 MB ~= 107 MB.
    float* A        = (float*)alloc((size_t)N * 256 * 4);
    float* attn_agg = A;
    float* mean_agg = A + (size_t)N * D;
    float* e_buf    = (float*)alloc((size_t)E_ER * 4);
    u32*   key      = (u32*)alloc((size_t)N * 4);
    float* ssum     = (float*)alloc((size_t)N * 4);
    float* cnt      = (float*)alloc((size_t)N * 4);

    k_init<<<(N + 255) / 256, 256, 0, stream>>>(ssum, cnt, key, N);
    k_precompute<<<(N + 7) / 8, 256, 0, stream>>>(emb, Wattn, A, N);
    k_edge_logit<<<(E_ER + 3) / 4, 256, 0, stream>>>(A, er_src, er_dst, Wattn_b, w0w, w0b,
                                                     e_buf, key, E_ER);
    // A dead; zero its space as attn_agg|mean_agg
    k_init2<<<(N * 256 + 255) / 256, 256, 0, stream>>>(A, N);
    k_exp<<<(E_ER + 255) / 256, 256, 0, stream>>>(er_src, e_buf, key, ssum, E_ER);
    k_attn_agg<<<(int)(((long long)E_ER * 64 + 255) / 256), 256, 0, stream>>>(
        emb, er_src, er_dst, e_buf, ssum, attn_agg, E_ER);
    // er: gather emb[src], scatter into dst, weight 1
    k_mean<<<(int)(((long long)E_ER * 64 + 255) / 256), 256, 0, stream>>>(
        emb, er_src, er_dst, ee_w, mean_agg, cnt, E_ER, 0);
    // ee: gather emb[dst], scatter into src, weight w[e]
    k_mean<<<(int)(((long long)E_EE * 64 + 255) / 256), 256, 0, stream>>>(
        emb, ee_dst, ee_src, ee_w, mean_agg, cnt, E_EE, 1);
    // rr: gather emb[dst], scatter into src, weight 1
    k_mean<<<(int)(((long long)E_RR * 64 + 255) / 256), 256, 0, stream>>>(
        emb, rr_dst, rr_src, ee_w, mean_agg, cnt, E_RR, 0);
    k_final<<<(N + 15) / 16, 256, 0, stream>>>(emb, attn_agg, mean_agg, cnt,
                                               W1, b1, W2, b2, W3, b3, out, N);
}

// Round 4
// 1436.588 us; speedup vs baseline: 2.4206x; 2.4206x over previous
//
#include <hip/hip_runtime.h>

typedef unsigned int u32;
typedef unsigned short u16;

#define D 128

__device__ inline float b2f(u32 h) { return __uint_as_float((h & 0xffffu) << 16); }
__device__ inline u16 f2b(float f) {
    u32 u = __float_as_uint(f);
    return (u16)((u + 0x7fffu + ((u >> 16) & 1u)) >> 16);
}

// ---------------- zero int array ----------------
__global__ void k_zero(int* p, int n) {
    int i = blockIdx.x * 256 + threadIdx.x;
    if (i < n) p[i] = 0;
}

// ---------------- histogram ----------------
__global__ void k_hist(const int* __restrict__ idx, int* __restrict__ cnt, int E) {
    int i = blockIdx.x * 256 + threadIdx.x;
    if (i < E) atomicAdd(cnt + idx[i], 1);
}

// ---------------- exclusive scan, 3-phase (1024 elems / block) ----------------
__global__ void k_scan1(const int* __restrict__ cnt, int n, int* __restrict__ out,
                        int* __restrict__ bsum) {
    __shared__ int sh[256];
    int t = threadIdx.x;
    int base = blockIdx.x * 1024 + t * 4;
    int v0 = (base < n) ? cnt[base] : 0;
    int v1 = (base + 1 < n) ? cnt[base + 1] : 0;
    int v2 = (base + 2 < n) ? cnt[base + 2] : 0;
    int v3 = (base + 3 < n) ? cnt[base + 3] : 0;
    int s4 = v0 + v1 + v2 + v3;
    sh[t] = s4;
    __syncthreads();
    for (int o = 1; o < 256; o <<= 1) {
        int x = (t >= o) ? sh[t - o] : 0;
        __syncthreads();
        sh[t] += x;
        __syncthreads();
    }
    int p = sh[t] - s4;  // exclusive prefix for this thread
    if (t == 255) bsum[blockIdx.x] = sh[255];
    if (base < n) out[base] = p;
    p += v0;
    if (base + 1 < n) out[base + 1] = p;
    p += v1;
    if (base + 2 < n) out[base + 2] = p;
    p += v2;
    if (base + 3 < n) out[base + 3] = p;
}

__global__ void k_scan2(int* bsum, int nb, int* total_out) {
    __shared__ int sh[256];
    int t = threadIdx.x;
    int v = (t < nb) ? bsum[t] : 0;
    sh[t] = v;
    __syncthreads();
    for (int o = 1; o < 256; o <<= 1) {
        int x = (t >= o) ? sh[t - o] : 0;
        __syncthreads();
        sh[t] += x;
        __syncthreads();
    }
    if (t < nb) bsum[t] = sh[t] - v;
    if (t == 255) *total_out = sh[255];
}

__global__ void k_scan3(int* __restrict__ out, const int* __restrict__ bsum, int n,
                        int* __restrict__ cur) {
    int i = blockIdx.x * 256 + threadIdx.x;
    if (i < n) {
        int v = out[i] + bsum[i >> 10];
        out[i] = v;
        cur[i] = v;
    }
}

// ---------------- CSR slot fill ----------------
__global__ void k_fill_attn(const int* __restrict__ src, const int* __restrict__ dst,
                            int* __restrict__ cur, int* __restrict__ lst, int E) {
    int i = blockIdx.x * 256 + threadIdx.x;
    if (i >= E) return;
    int p = atomicAdd(cur + src[i], 1);
    lst[p] = dst[i];
}

// mode 0: weight 1; mode 1: weight w[i]
__global__ void k_fill_mean(const int* __restrict__ sct, const int* __restrict__ gat,
                            const float* __restrict__ w, int* __restrict__ cur,
                            int* __restrict__ gid, float* __restrict__ gw, int E, int mode) {
    int i = blockIdx.x * 256 + threadIdx.x;
    if (i >= E) return;
    int p = atomicAdd(cur + sct[i], 1);
    gid[p] = gat[i];
    gw[p] = mode ? w[i] : 1.f;
}

// --- A = emb @ Wcat^T (bf16 out). A[n][d<128]=W_r@emb[n], A[n][128+d]=W_h@emb[n] ---
__global__ __launch_bounds__(256) void k_precompute(const float* __restrict__ emb,
                                                    const float* __restrict__ Wattn,
                                                    u16* __restrict__ A, int N) {
    __shared__ float semb[8][D];
    int nb = blockIdx.x * 8;
    int tid = threadIdx.x;
    for (int i = tid; i < 8 * D; i += 256) {
        int n = nb + (i >> 7);
        semb[i >> 7][i & 127] = (n < N) ? emb[(size_t)n * D + (i & 127)] : 0.f;
    }
    __syncthreads();
    int d = tid;  // 0..255
    const float* wrow = (d < D) ? (Wattn + (size_t)d * 256)
                                : (Wattn + (size_t)(d - 128) * 256 + 128);
    float acc[8];
#pragma unroll
    for (int n = 0; n < 8; n++) acc[n] = 0.f;
    for (int k = 0; k < D; k += 4) {
        float4 w = *(const float4*)(wrow + k);
#pragma unroll
        for (int n = 0; n < 8; n++) {
            acc[n] += w.x * semb[n][k] + w.y * semb[n][k + 1] +
                      w.z * semb[n][k + 2] + w.w * semb[n][k + 3];
        }
    }
#pragma unroll
    for (int n = 0; n < 8; n++) {
        int nn = nb + n;
        if (nn < N) A[(size_t)nn * 256 + d] = f2b(acc[n]);
    }
}

// ------- fused attention: logits + online softmax + weighted gather -------
// one wave per node; lanes hold 2 dims each
__global__ __launch_bounds__(256) void k_attn(const u16* __restrict__ A,
                                              const int* __restrict__ off,
                                              const int* __restrict__ lst,
                                              const float* __restrict__ emb,
                                              const float* __restrict__ Wb,
                                              const float* __restrict__ w0w,
                                              const float* __restrict__ w0b,
                                              float* __restrict__ attn_agg, int N) {
    int node = blockIdx.x * 4 + (threadIdx.x >> 6);
    if (node >= N) return;
    int lane = threadIdx.x & 63;
    u32 ah = *(const u32*)(A + (size_t)node * 256 + 128 + 2 * lane);
    float ahx = b2f(ah), ahy = b2f(ah >> 16);
    float2 bb = *(const float2*)(Wb + 2 * lane);
    float2 ww = *(const float2*)(w0w + 2 * lane);
    float w0bias = w0b[0];
    int s0 = off[node], s1 = off[node + 1];
    float m = 0.f, l = 0.f, ox = 0.f, oy = 0.f;  // m init 0 == ref's max(segmax, 0)
    for (int s = s0; s < s1; ++s) {
        int dst = lst[s];
        u32 ar = *(const u32*)(A + (size_t)dst * 256 + 2 * lane);
        float p = tanhf(b2f(ar) + ahx + bb.x) * ww.x +
                  tanhf(b2f(ar >> 16) + ahy + bb.y) * ww.y;
#pragma unroll
        for (int o = 32; o; o >>= 1) p += __shfl_xor(p, o);
        float v = p + w0bias;
        float2 ev = *(const float2*)(emb + (size_t)dst * D + 2 * lane);
        if (v > m) {
            float sc = __expf(m - v);
            l *= sc; ox *= sc; oy *= sc;
            m = v;
        }
        float w = __expf(v - m);
        l += w;
        ox += w * ev.x;
        oy += w * ev.y;
    }
    float inv = 1.f / (l + 1e-9f);
    float* o = attn_agg + (size_t)node * D + 2 * lane;
    o[0] = ox * inv;
    o[1] = oy * inv;
}

// ---------------- unified mean gather: one wave per node ----------------
__global__ __launch_bounds__(256) void k_mean_g(const int* __restrict__ off,
                                                const int* __restrict__ gid,
                                                const float* __restrict__ gw,
                                                const float* __restrict__ emb,
                                                float* __restrict__ mean_agg, int N) {
    int node = blockIdx.x * 4 + (threadIdx.x >> 6);
    if (node >= N) return;
    int lane = threadIdx.x & 63;
    int s0 = off[node], s1 = off[node + 1];
    float ax = 0.f, ay = 0.f, c = 0.f;
    for (int s = s0; s < s1; ++s) {
        int g = gid[s];
        float w = gw[s];
        float2 v = *(const float2*)(emb + (size_t)g * D + 2 * lane);
        ax += w * v.x;
        ay += w * v.y;
        c += w;
    }
    c = c > 1.f ? c : 1.f;
    float* o = mean_agg + (size_t)node * D + 2 * lane;
    o[0] = ax / c;
    o[1] = ay / c;
}

// ---------------- fused epilogue: 3 matvecs + tanh + sum ----------------
__global__ __launch_bounds__(256) void k_final(const float* __restrict__ emb,
                                               const float* __restrict__ attn_agg,
                                               const float* __restrict__ mean_agg,
                                               const float* __restrict__ W1, const float* __restrict__ b1,
                                               const float* __restrict__ W2, const float* __restrict__ b2,
                                               const float* __restrict__ W3, const float* __restrict__ b3,
                                               float* __restrict__ out, int N) {
    __shared__ float s_e[16][D];
    __shared__ float s_a[16][D];
    __shared__ float s_m[16][D];
    int nb = blockIdx.x * 16;
    int tid = threadIdx.x;
    for (int i = tid; i < 16 * D; i += 256) {
        int n = nb + (i >> 7);
        int d = i & 127;
        int r = i >> 7;
        if (n < N) {
            s_e[r][d] = emb[(size_t)n * D + d];
            s_a[r][d] = attn_agg[(size_t)n * D + d];
            s_m[r][d] = mean_agg[(size_t)n * D + d];
        } else {
            s_e[r][d] = 0.f; s_a[r][d] = 0.f; s_m[r][d] = 0.f;
        }
    }
    __syncthreads();
    int d = tid & 127;
    int half = tid >> 7;
    const float* w1r = W1 + (size_t)d * D;
    const float* w2r = W2 + (size_t)d * D;
    const float* w3r = W3 + (size_t)d * D;
    float acc1[8], acc2[8], acc3[8];
#pragma unroll
    for (int n = 0; n < 8; n++) { acc1[n] = 0.f; acc2[n] = 0.f; acc3[n] = 0.f; }
    for (int k = 0; k < D; k += 4) {
        float4 w1 = *(const float4*)(w1r + k);
        float4 w2 = *(const float4*)(w2r + k);
        float4 w3 = *(const float4*)(w3r + k);
#pragma unroll
        for (int n = 0; n < 8; n++) {
            int nn = 2 * n + half;
            const float* pe = &s_e[nn][k];
            const float* pa = &s_a[nn][k];
            const float* pm = &s_m[nn][k];
            acc1[n] += w1.x * pe[0] + w1.y * pe[1] + w1.z * pe[2] + w1.w * pe[3];
            acc2[n] += w2.x * pa[0] + w2.y * pa[1] + w2.z * pa[2] + w2.w * pa[3];
            acc3[n] += w3.x * pm[0] + w3.y * pm[1] + w3.z * pm[2] + w3.w * pm[3];
        }
    }
    float bb1 = b1[d], bb2 = b2[d], bb3 = b3[d];
#pragma unroll
    for (int n = 0; n < 8; n++) {
        int gn = nb + 2 * n + half;
        if (gn < N)
            out[(size_t)gn * D + d] =
                tanhf(acc1[n] + bb1) + tanhf(acc2[n] + bb2) + tanhf(acc3[n] + bb3);
    }
}

extern "C" void kernel_launch(void* const* d_in, const int* in_sizes, int n_in,
                              void* d_out, int out_size, void* d_ws, size_t ws_size,
                              hipStream_t stream) {
    const float* emb     = (const float*)d_in[0];
    const int*   er_src  = (const int*)d_in[1];
    const int*   er_dst  = (const int*)d_in[2];
    const int*   ee_src  = (const int*)d_in[3];
    const int*   ee_dst  = (const int*)d_in[4];
    const float* ee_w    = (const float*)d_in[5];
    const int*   rr_src  = (const int*)d_in[6];
    const int*   rr_dst  = (const int*)d_in[7];
    const float* Wattn   = (const float*)d_in[8];
    const float* Wattn_b = (const float*)d_in[9];
    const float* w0w     = (const float*)d_in[10];
    const float* w0b     = (const float*)d_in[11];
    const float* W1      = (const float*)d_in[12];
    const float* b1      = (const float*)d_in[13];
    const float* W2      = (const float*)d_in[14];
    const float* b2      = (const float*)d_in[15];
    const float* W3      = (const float*)d_in[16];
    const float* b3      = (const float*)d_in[17];
    float* out = (float*)d_out;

    int N    = in_sizes[0] / D;
    int E_ER = in_sizes[1];
    int E_EE = in_sizes[3];
    int E_RR = in_sizes[6];
    int E_M  = E_ER + E_EE + E_RR;

    char* ws = (char*)d_ws;
    size_t off_b = 0;
    auto alloc = [&](size_t bytes) -> void* {
        void* p = ws + off_b;
        off_b += (bytes + 255) & ~(size_t)255;
        return p;
    };
    // A (N x 256 bf16 = N*512B) aliases mean_agg (N x 128 f32 = N*512B):
    // A dead after k_attn, mean_agg written after.  Total ws ~= 123 MB.
    u16*   A        = (u16*)alloc((size_t)N * 256 * 2);
    float* mean_agg = (float*)A;
    float* attn_agg = (float*)alloc((size_t)N * D * 4);
    int*   cnt_src  = (int*)alloc((size_t)N * 4);
    int*   cnt_mean = (int*)alloc((size_t)N * 4);
    int*   off_src  = (int*)alloc((size_t)(N + 1) * 4);
    int*   off_mean = (int*)alloc((size_t)(N + 1) * 4);
    int*   cur_src  = (int*)alloc((size_t)N * 4);
    int*   cur_mean = (int*)alloc((size_t)N * 4);
    int*   bsumA    = (int*)alloc(256 * 4);
    int*   bsumB    = (int*)alloc(256 * 4);
    int*   er_lst   = (int*)alloc((size_t)E_ER * 4);
    int*   gid      = (int*)alloc((size_t)E_M * 4);
    float* gw       = (float*)alloc((size_t)E_M * 4);

    int nb_scan = (N + 1023) / 1024;  // 98 for N=100k (must be <= 256)

    // --- CSR build ---
    k_zero<<<(N + 255) / 256, 256, 0, stream>>>(cnt_src, N);
    k_zero<<<(N + 255) / 256, 256, 0, stream>>>(cnt_mean, N);
    k_hist<<<(E_ER + 255) / 256, 256, 0, stream>>>(er_src, cnt_src, E_ER);
    k_hist<<<(E_ER + 255) / 256, 256, 0, stream>>>(er_dst, cnt_mean, E_ER);
    k_hist<<<(E_EE + 255) / 256, 256, 0, stream>>>(ee_src, cnt_mean, E_EE);
    k_hist<<<(E_RR + 255) / 256, 256, 0, stream>>>(rr_src, cnt_mean, E_RR);
    k_scan1<<<nb_scan, 256, 0, stream>>>(cnt_src, N, off_src, bsumA);
    k_scan2<<<1, 256, 0, stream>>>(bsumA, nb_scan, off_src + N);
    k_scan3<<<(N + 255) / 256, 256, 0, stream>>>(off_src, bsumA, N, cur_src);
    k_scan1<<<nb_scan, 256, 0, stream>>>(cnt_mean, N, off_mean, bsumB);
    k_scan2<<<1, 256, 0, stream>>>(bsumB, nb_scan, off_mean + N);
    k_scan3<<<(N + 255) / 256, 256, 0, stream>>>(off_mean, bsumB, N, cur_mean);
    k_fill_attn<<<(E_ER + 255) / 256, 256, 0, stream>>>(er_src, er_dst, cur_src, er_lst, E_ER);
    // mean CSR: er contributes (dst <- src, 1), ee (src <- dst, w), rr (src <- dst, 1)
    k_fill_mean<<<(E_ER + 255) / 256, 256, 0, stream>>>(er_dst, er_src, ee_w, cur_mean, gid, gw, E_ER, 0);
    k_fill_mean<<<(E_EE + 255) / 256, 256, 0, stream>>>(ee_src, ee_dst, ee_w, cur_mean, gid, gw, E_EE, 1);
    k_fill_mean<<<(E_RR + 255) / 256, 256, 0, stream>>>(rr_src, rr_dst, ee_w, cur_mean, gid, gw, E_RR, 0);

    // --- compute ---
    k_precompute<<<(N + 7) / 8, 256, 0, stream>>>(emb, Wattn, A, N);
    k_attn<<<(N + 3) / 4, 256, 0, stream>>>(A, off_src, er_lst, emb, Wattn_b, w0w, w0b,
                                            attn_agg, N);
    // A dead from here; its space becomes mean_agg
    k_mean_g<<<(N + 3) / 4, 256, 0, stream>>>(off_mean, gid, gw, emb, mean_agg, N);
    k_final<<<(N + 15) / 16, 256, 0, stream>>>(emb, attn_agg, mean_agg,
                                               W1, b1, W2, b2, W3, b3, out, N);
}

// Round 5
// 905.330 us; speedup vs baseline: 3.8411x; 1.5868x over previous
//
#include <hip/hip_runtime.h>

typedef unsigned int u32;
typedef unsigned short u16;

#define D 128

typedef __attribute__((ext_vector_type(8))) short bf16x8;
typedef __attribute__((ext_vector_type(4))) float f32x4;
#define MFMA16x16(a, b, c) __builtin_amdgcn_mfma_f32_16x16x32_bf16(a, b, c, 0, 0, 0)

__device__ inline float b2f(u32 h) { return __uint_as_float((h & 0xffffu) << 16); }
__device__ inline u16 f2b(float f) {
    u32 u = __float_as_uint(f);
    return (u16)((u + 0x7fffu + ((u >> 16) & 1u)) >> 16);
}
__device__ inline float tanh_fast(float x) {
    x = fminf(fmaxf(x, -15.f), 15.f);
    float e = __expf(2.f * x);
    return (e - 1.f) * __builtin_amdgcn_rcpf(e + 1.f);
}

// ---------------- zero int array ----------------
__global__ void k_zero(int* p, int n) {
    int i = blockIdx.x * 256 + threadIdx.x;
    if (i < n) p[i] = 0;
}

// ---------------- histogram ----------------
__global__ void k_hist(const int* __restrict__ idx, int* __restrict__ cnt, int E) {
    int i = blockIdx.x * 256 + threadIdx.x;
    if (i < E) atomicAdd(cnt + idx[i], 1);
}

// ---------------- exclusive scan, 3-phase (1024 elems / block) ----------------
__global__ void k_scan1(const int* __restrict__ cnt, int n, int* __restrict__ out,
                        int* __restrict__ bsum) {
    __shared__ int sh[256];
    int t = threadIdx.x;
    int base = blockIdx.x * 1024 + t * 4;
    int v0 = (base < n) ? cnt[base] : 0;
    int v1 = (base + 1 < n) ? cnt[base + 1] : 0;
    int v2 = (base + 2 < n) ? cnt[base + 2] : 0;
    int v3 = (base + 3 < n) ? cnt[base + 3] : 0;
    int s4 = v0 + v1 + v2 + v3;
    sh[t] = s4;
    __syncthreads();
    for (int o = 1; o < 256; o <<= 1) {
        int x = (t >= o) ? sh[t - o] : 0;
        __syncthreads();
        sh[t] += x;
        __syncthreads();
    }
    int p = sh[t] - s4;
    if (t == 255) bsum[blockIdx.x] = sh[255];
    if (base < n) out[base] = p;
    p += v0;
    if (base + 1 < n) out[base + 1] = p;
    p += v1;
    if (base + 2 < n) out[base + 2] = p;
    p += v2;
    if (base + 3 < n) out[base + 3] = p;
}

__global__ void k_scan2(int* bsum, int nb, int* total_out) {
    __shared__ int sh[256];
    int t = threadIdx.x;
    int v = (t < nb) ? bsum[t] : 0;
    sh[t] = v;
    __syncthreads();
    for (int o = 1; o < 256; o <<= 1) {
        int x = (t >= o) ? sh[t - o] : 0;
        __syncthreads();
        sh[t] += x;
        __syncthreads();
    }
    if (t < nb) bsum[t] = sh[t] - v;
    if (t == 255) *total_out = sh[255];
}

__global__ void k_scan3(int* __restrict__ out, const int* __restrict__ bsum, int n,
                        int* __restrict__ cur) {
    int i = blockIdx.x * 256 + threadIdx.x;
    if (i < n) {
        int v = out[i] + bsum[i >> 10];
        out[i] = v;
        cur[i] = v;
    }
}

// ---------------- CSR slot fill ----------------
__global__ void k_fill_attn(const int* __restrict__ src, const int* __restrict__ dst,
                            int* __restrict__ cur, int* __restrict__ lst, int E) {
    int i = blockIdx.x * 256 + threadIdx.x;
    if (i >= E) return;
    int p = atomicAdd(cur + src[i], 1);
    lst[p] = dst[i];
}

__global__ void k_fill_mean(const int* __restrict__ sct, const int* __restrict__ gat,
                            const float* __restrict__ w, int* __restrict__ cur,
                            int* __restrict__ gid, float* __restrict__ gw, int E, int mode) {
    int i = blockIdx.x * 256 + threadIdx.x;
    if (i >= E) return;
    int p = atomicAdd(cur + sct[i], 1);
    gid[p] = gat[i];
    gw[p] = mode ? w[i] : 1.f;
}

// ---------------- casts ----------------
__global__ void k_cast4(const float* __restrict__ src, u16* __restrict__ dst, int n4) {
    int i = blockIdx.x * 256 + threadIdx.x;
    if (i >= n4) return;
    float4 v = ((const float4*)src)[i];
    ushort4 o;
    o.x = f2b(v.x); o.y = f2b(v.y); o.z = f2b(v.z); o.w = f2b(v.w);
    ((ushort4*)dst)[i] = o;
}

__global__ void k_cast1(const float* __restrict__ src, u16* __restrict__ dst, int n) {
    int i = blockIdx.x * 256 + threadIdx.x;
    if (i < n) dst[i] = f2b(src[i]);
}

// Wcat_h[dd][k] (256x128): dd<128 -> Wattn[dd][k]; else Wattn[dd-128][128+k]
__global__ void k_castWcat(const float* __restrict__ Wattn, u16* __restrict__ Wcat, int n) {
    int i = blockIdx.x * 256 + threadIdx.x;
    if (i >= n) return;
    int dd = i >> 7, k = i & 127;
    float v = (dd < 128) ? Wattn[(size_t)dd * 256 + k]
                         : Wattn[(size_t)(dd - 128) * 256 + 128 + k];
    Wcat[i] = f2b(v);
}

// --- A = embh @ Wcat^T via MFMA. A[n][dd] bf16, dd in [0,256) ---
__global__ __launch_bounds__(256) void k_precompute_mfma(const u16* __restrict__ embh,
                                                         const u16* __restrict__ Wcat,
                                                         u16* __restrict__ A, int N) {
    __shared__ u16 sX[64][136];  // +8 bf16 pad per row
    int nb = blockIdx.x * 64;
    int tid = threadIdx.x;
    for (int i = tid; i < 1024; i += 256) {
        int row = i >> 4, c8 = i & 15;
        int n = nb + row;
        uint4 v = make_uint4(0u, 0u, 0u, 0u);
        if (n < N) v = *(const uint4*)(embh + (size_t)n * 128 + c8 * 8);
        *(uint4*)&sX[row][c8 * 8] = v;
    }
    __syncthreads();
    int wid = tid >> 6, lane = tid & 63;
    int quad = lane >> 4, l15 = lane & 15;
#pragma unroll
    for (int ns = 0; ns < 4; ns++) {
        int dbase = (wid * 4 + ns) * 16;
        bf16x8 b[4];
#pragma unroll
        for (int ks = 0; ks < 4; ks++)
            b[ks] = *(const bf16x8*)(Wcat + (size_t)(dbase + l15) * 128 + ks * 32 + quad * 8);
#pragma unroll
        for (int ms = 0; ms < 4; ms++) {
            f32x4 acc = {0.f, 0.f, 0.f, 0.f};
#pragma unroll
            for (int ks = 0; ks < 4; ks++) {
                bf16x8 a = *(const bf16x8*)&sX[ms * 16 + l15][ks * 32 + quad * 8];
                acc = MFMA16x16(a, b[ks], acc);
            }
#pragma unroll
            for (int r = 0; r < 4; r++) {
                int row = nb + ms * 16 + quad * 4 + r;
                if (row < N) A[(size_t)row * 256 + dbase + l15] = f2b(acc[r]);
            }
        }
    }
}

// ------- fused attention: logits + online softmax + weighted gather -------
__global__ __launch_bounds__(256) void k_attn(const u16* __restrict__ A,
                                              const int* __restrict__ off,
                                              const int* __restrict__ lst,
                                              const u16* __restrict__ embh,
                                              const float* __restrict__ Wb,
                                              const float* __restrict__ w0w,
                                              const float* __restrict__ w0b,
                                              u16* __restrict__ attn_h, int N) {
    int node = blockIdx.x * 4 + (threadIdx.x >> 6);
    if (node >= N) return;
    int lane = threadIdx.x & 63;
    u32 ah = *(const u32*)(A + (size_t)node * 256 + 128 + 2 * lane);
    float ahx = b2f(ah), ahy = b2f(ah >> 16);
    float2 bb = *(const float2*)(Wb + 2 * lane);
    float2 ww = *(const float2*)(w0w + 2 * lane);
    float w0bias = w0b[0];
    int s0 = off[node], s1 = off[node + 1];
    float m = 0.f, l = 0.f, ox = 0.f, oy = 0.f;  // m init 0 == ref's max(segmax, 0)
    for (int s = s0; s < s1; ++s) {
        int dst = lst[s];
        u32 ar = *(const u32*)(A + (size_t)dst * 256 + 2 * lane);
        float p = tanh_fast(b2f(ar) + ahx + bb.x) * ww.x +
                  tanh_fast(b2f(ar >> 16) + ahy + bb.y) * ww.y;
#pragma unroll
        for (int o = 32; o; o >>= 1) p += __shfl_xor(p, o);
        float v = p + w0bias;
        u32 ev = *(const u32*)(embh + (size_t)dst * 128 + 2 * lane);
        if (v > m) {
            float sc = __expf(m - v);
            l *= sc; ox *= sc; oy *= sc;
            m = v;
        }
        float w = __expf(v - m);
        l += w;
        ox += w * b2f(ev);
        oy += w * b2f(ev >> 16);
    }
    float inv = 1.f / (l + 1e-9f);
    u32 o = (u32)f2b(ox * inv) | ((u32)f2b(oy * inv) << 16);
    *(u32*)(attn_h + (size_t)node * 128 + 2 * lane) = o;
}

// ---------------- unified mean gather: one wave per node ----------------
__global__ __launch_bounds__(256) void k_mean_g(const int* __restrict__ off,
                                                const int* __restrict__ gid,
                                                const float* __restrict__ gw,
                                                const u16* __restrict__ embh,
                                                u16* __restrict__ mean_h, int N) {
    int node = blockIdx.x * 4 + (threadIdx.x >> 6);
    if (node >= N) return;
    int lane = threadIdx.x & 63;
    int s0 = off[node], s1 = off[node + 1];
    float ax = 0.f, ay = 0.f, c = 0.f;
    for (int s = s0; s < s1; ++s) {
        int g = gid[s];
        float w = gw[s];
        u32 v = *(const u32*)(embh + (size_t)g * 128 + 2 * lane);
        ax += w * b2f(v);
        ay += w * b2f(v >> 16);
        c += w;
    }
    c = c > 1.f ? c : 1.f;
    float inv = 1.f / c;
    u32 o = (u32)f2b(ax * inv) | ((u32)f2b(ay * inv) << 16);
    *(u32*)(mean_h + (size_t)node * 128 + 2 * lane) = o;
}

// --------- fused epilogue via MFMA: out = sum of 3 tanh(GEMM + bias) ---------
__global__ __launch_bounds__(256) void k_final_mfma(const u16* __restrict__ embh,
                                                    const u16* __restrict__ attn_h,
                                                    const u16* __restrict__ mean_h,
                                                    const u16* __restrict__ W123h,
                                                    const float* __restrict__ b1,
                                                    const float* __restrict__ b2,
                                                    const float* __restrict__ b3,
                                                    float* __restrict__ out, int N) {
    __shared__ u16 sX[3][64][136];
    int nb = blockIdx.x * 64;
    int tid = threadIdx.x;
    const u16* srcs[3] = {embh, attn_h, mean_h};
#pragma unroll
    for (int arr = 0; arr < 3; arr++) {
        const u16* s = srcs[arr];
        for (int i = tid; i < 1024; i += 256) {
            int row = i >> 4, c8 = i & 15;
            int n = nb + row;
            uint4 v = make_uint4(0u, 0u, 0u, 0u);
            if (n < N) v = *(const uint4*)(s + (size_t)n * 128 + c8 * 8);
            *(uint4*)&sX[arr][row][c8 * 8] = v;
        }
    }
    __syncthreads();
    int wid = tid >> 6, lane = tid & 63;
    int quad = lane >> 4, l15 = lane & 15;
#pragma unroll
    for (int ns = 0; ns < 2; ns++) {
        int dbase = (wid * 2 + ns) * 16;
        int d = dbase + l15;
        bf16x8 b[3][4];
#pragma unroll
        for (int arr = 0; arr < 3; arr++)
#pragma unroll
            for (int ks = 0; ks < 4; ks++)
                b[arr][ks] = *(const bf16x8*)(W123h + (size_t)arr * 16384 +
                                              (size_t)d * 128 + ks * 32 + quad * 8);
        float bias0 = b1[d], bias1 = b2[d], bias2 = b3[d];
#pragma unroll
        for (int ms = 0; ms < 4; ms++) {
            f32x4 acc0 = {0.f, 0.f, 0.f, 0.f};
            f32x4 acc1 = {0.f, 0.f, 0.f, 0.f};
            f32x4 acc2 = {0.f, 0.f, 0.f, 0.f};
#pragma unroll
            for (int ks = 0; ks < 4; ks++) {
                bf16x8 a0 = *(const bf16x8*)&sX[0][ms * 16 + l15][ks * 32 + quad * 8];
                bf16x8 a1 = *(const bf16x8*)&sX[1][ms * 16 + l15][ks * 32 + quad * 8];
                bf16x8 a2 = *(const bf16x8*)&sX[2][ms * 16 + l15][ks * 32 + quad * 8];
                acc0 = MFMA16x16(a0, b[0][ks], acc0);
                acc1 = MFMA16x16(a1, b[1][ks], acc1);
                acc2 = MFMA16x16(a2, b[2][ks], acc2);
            }
#pragma unroll
            for (int r = 0; r < 4; r++) {
                int row = nb + ms * 16 + quad * 4 + r;
                if (row < N)
                    out[(size_t)row * 128 + d] = tanh_fast(acc0[r] + bias0) +
                                                 tanh_fast(acc1[r] + bias1) +
                                                 tanh_fast(acc2[r] + bias2);
            }
        }
    }
}

extern "C" void kernel_launch(void* const* d_in, const int* in_sizes, int n_in,
                              void* d_out, int out_size, void* d_ws, size_t ws_size,
                              hipStream_t stream) {
    const float* emb     = (const float*)d_in[0];
    const int*   er_src  = (const int*)d_in[1];
    const int*   er_dst  = (const int*)d_in[2];
    const int*   ee_src  = (const int*)d_in[3];
    const int*   ee_dst  = (const int*)d_in[4];
    const float* ee_w    = (const float*)d_in[5];
    const int*   rr_src  = (const int*)d_in[6];
    const int*   rr_dst  = (const int*)d_in[7];
    const float* Wattn   = (const float*)d_in[8];
    const float* Wattn_b = (const float*)d_in[9];
    const float* w0w     = (const float*)d_in[10];
    const float* w0b     = (const float*)d_in[11];
    const float* W1      = (const float*)d_in[12];
    const float* b1      = (const float*)d_in[13];
    const float* W2      = (const float*)d_in[14];
    const float* b2      = (const float*)d_in[15];
    const float* W3      = (const float*)d_in[16];
    const float* b3      = (const float*)d_in[17];
    float* out = (float*)d_out;

    int N    = in_sizes[0] / D;
    int E_ER = in_sizes[1];
    int E_EE = in_sizes[3];
    int E_RR = in_sizes[6];
    int E_M  = E_ER + E_EE + E_RR;

    char* ws = (char*)d_ws;
    size_t off_b = 0;
    auto alloc = [&](size_t bytes) -> void* {
        void* p = ws + off_b;
        off_b += (bytes + 255) & ~(size_t)255;
        return p;
    };
    // A (N x 256 bf16) dead after k_attn; mean_h (N x 128 bf16) aliases its
    // first half.  Total ws ~= 25.6 + 51.2 + 25.6 + ~21.7 MB ~= 124 MB.
    u16*   embh   = (u16*)alloc((size_t)N * 128 * 2);
    u16*   A      = (u16*)alloc((size_t)N * 256 * 2);
    u16*   mean_h = A;
    u16*   attn_h = (u16*)alloc((size_t)N * 128 * 2);
    u16*   Wcat_h = (u16*)alloc(256 * 128 * 2);
    u16*   W123h  = (u16*)alloc(3 * 128 * 128 * 2);
    int*   cnt_src  = (int*)alloc((size_t)N * 4);
    int*   cnt_mean = (int*)alloc((size_t)N * 4);
    int*   off_src  = (int*)alloc((size_t)(N + 1) * 4);
    int*   off_mean = (int*)alloc((size_t)(N + 1) * 4);
    int*   cur_src  = (int*)alloc((size_t)N * 4);
    int*   cur_mean = (int*)alloc((size_t)N * 4);
    int*   bsumA    = (int*)alloc(256 * 4);
    int*   bsumB    = (int*)alloc(256 * 4);
    int*   er_lst   = (int*)alloc((size_t)E_ER * 4);
    int*   gid      = (int*)alloc((size_t)E_M * 4);
    float* gw       = (float*)alloc((size_t)E_M * 4);

    int nb_scan = (N + 1023) / 1024;

    // --- CSR build ---
    k_zero<<<(N + 255) / 256, 256, 0, stream>>>(cnt_src, N);
    k_zero<<<(N + 255) / 256, 256, 0, stream>>>(cnt_mean, N);
    k_hist<<<(E_ER + 255) / 256, 256, 0, stream>>>(er_src, cnt_src, E_ER);
    k_hist<<<(E_ER + 255) / 256, 256, 0, stream>>>(er_dst, cnt_mean, E_ER);
    k_hist<<<(E_EE + 255) / 256, 256, 0, stream>>>(ee_src, cnt_mean, E_EE);
    k_hist<<<(E_RR + 255) / 256, 256, 0, stream>>>(rr_src, cnt_mean, E_RR);
    k_scan1<<<nb_scan, 256, 0, stream>>>(cnt_src, N, off_src, bsumA);
    k_scan2<<<1, 256, 0, stream>>>(bsumA, nb_scan, off_src + N);
    k_scan3<<<(N + 255) / 256, 256, 0, stream>>>(off_src, bsumA, N, cur_src);
    k_scan1<<<nb_scan, 256, 0, stream>>>(cnt_mean, N, off_mean, bsumB);
    k_scan2<<<1, 256, 0, stream>>>(bsumB, nb_scan, off_mean + N);
    k_scan3<<<(N + 255) / 256, 256, 0, stream>>>(off_mean, bsumB, N, cur_mean);
    k_fill_attn<<<(E_ER + 255) / 256, 256, 0, stream>>>(er_src, er_dst, cur_src, er_lst, E_ER);
    k_fill_mean<<<(E_ER + 255) / 256, 256, 0, stream>>>(er_dst, er_src, ee_w, cur_mean, gid, gw, E_ER, 0);
    k_fill_mean<<<(E_EE + 255) / 256, 256, 0, stream>>>(ee_src, ee_dst, ee_w, cur_mean, gid, gw, E_EE, 1);
    k_fill_mean<<<(E_RR + 255) / 256, 256, 0, stream>>>(rr_src, rr_dst, ee_w, cur_mean, gid, gw, E_RR, 0);

    // --- casts ---
    k_cast4<<<((N * 128 / 4) + 255) / 256, 256, 0, stream>>>(emb, embh, N * 128 / 4);
    k_castWcat<<<(256 * 128 + 255) / 256, 256, 0, stream>>>(Wattn, Wcat_h, 256 * 128);
    k_cast1<<<(16384 + 255) / 256, 256, 0, stream>>>(W1, W123h, 16384);
    k_cast1<<<(16384 + 255) / 256, 256, 0, stream>>>(W2, W123h + 16384, 16384);
    k_cast1<<<(16384 + 255) / 256, 256, 0, stream>>>(W3, W123h + 32768, 16384);

    // --- compute ---
    k_precompute_mfma<<<(N + 63) / 64, 256, 0, stream>>>(embh, Wcat_h, A, N);
    k_attn<<<(N + 3) / 4, 256, 0, stream>>>(A, off_src, er_lst, embh, Wattn_b, w0w, w0b,
                                            attn_h, N);
    // A dead; its space becomes mean_h
    k_mean_g<<<(N + 3) / 4, 256, 0, stream>>>(off_mean, gid, gw, embh, mean_h, N);
    k_final_mfma<<<(N + 63) / 64, 256, 0, stream>>>(embh, attn_h, mean_h, W123h,
                                                    b1, b2, b3, out, N);
}

// Round 6
// 770.145 us; speedup vs baseline: 4.5153x; 1.1755x over previous
//
#include <hip/hip_runtime.h>

typedef unsigned int u32;
typedef unsigned short u16;

#define D 128

typedef __attribute__((ext_vector_type(8))) short bf16x8;
typedef __attribute__((ext_vector_type(4))) float f32x4;
#define MFMA16x16(a, b, c) __builtin_amdgcn_mfma_f32_16x16x32_bf16(a, b, c, 0, 0, 0)

__device__ inline float b2f(u32 h) { return __uint_as_float((h & 0xffffu) << 16); }
__device__ inline u16 f2b(float f) {
    u32 u = __float_as_uint(f);
    return (u16)((u + 0x7fffu + ((u >> 16) & 1u)) >> 16);
}
__device__ inline float tanh_fast(float x) {
    x = fminf(fmaxf(x, -15.f), 15.f);
    float e = __expf(2.f * x);
    return (e - 1.f) * __builtin_amdgcn_rcpf(e + 1.f);
}

// ---------------- zero int array ----------------
__global__ void k_zero(int* p, int n) {
    int i = blockIdx.x * 256 + threadIdx.x;
    if (i < n) p[i] = 0;
}

// ------- fused histogram over all 4 edge lists -------
__global__ void k_hist_all(const int* __restrict__ er_src, const int* __restrict__ er_dst,
                           const int* __restrict__ ee_src, const int* __restrict__ rr_src,
                           int* __restrict__ cnt_src, int* __restrict__ cnt_mean,
                           int E_ER, int E_EE, int E_RR) {
    int i = blockIdx.x * 256 + threadIdx.x;
    if (i < E_ER) { atomicAdd(cnt_src + er_src[i], 1); return; }
    i -= E_ER;
    if (i < E_ER) { atomicAdd(cnt_mean + er_dst[i], 1); return; }
    i -= E_ER;
    if (i < E_EE) { atomicAdd(cnt_mean + ee_src[i], 1); return; }
    i -= E_EE;
    if (i < E_RR) atomicAdd(cnt_mean + rr_src[i], 1);
}

// ---------------- dual exclusive scan, 3-phase ----------------
__global__ void k_scan1_dual(const int* __restrict__ cnt2, int n,
                             int* __restrict__ off_src, int* __restrict__ off_mean,
                             int* __restrict__ bsum, int nbs) {
    __shared__ int sh[256];
    int b = blockIdx.x;
    const int* cnt = cnt2;
    int* out = off_src;
    int* bs = bsum;
    if (b >= nbs) { b -= nbs; cnt = cnt2 + n; out = off_mean; bs = bsum + 256; }
    int t = threadIdx.x;
    int base = b * 1024 + t * 4;
    int v0 = (base < n) ? cnt[base] : 0;
    int v1 = (base + 1 < n) ? cnt[base + 1] : 0;
    int v2 = (base + 2 < n) ? cnt[base + 2] : 0;
    int v3 = (base + 3 < n) ? cnt[base + 3] : 0;
    int s4 = v0 + v1 + v2 + v3;
    sh[t] = s4;
    __syncthreads();
    for (int o = 1; o < 256; o <<= 1) {
        int x = (t >= o) ? sh[t - o] : 0;
        __syncthreads();
        sh[t] += x;
        __syncthreads();
    }
    int p = sh[t] - s4;
    if (t == 255) bs[b] = sh[255];
    if (base < n) out[base] = p;
    p += v0;
    if (base + 1 < n) out[base + 1] = p;
    p += v1;
    if (base + 2 < n) out[base + 2] = p;
    p += v2;
    if (base + 3 < n) out[base + 3] = p;
}

__global__ void k_scan2_dual(int* __restrict__ bsum, int nb,
                             int* __restrict__ totA, int* __restrict__ totB) {
    __shared__ int sh[256];
    int* bs = bsum + blockIdx.x * 256;
    int* tot = blockIdx.x ? totB : totA;
    int t = threadIdx.x;
    int v = (t < nb) ? bs[t] : 0;
    sh[t] = v;
    __syncthreads();
    for (int o = 1; o < 256; o <<= 1) {
        int x = (t >= o) ? sh[t - o] : 0;
        __syncthreads();
        sh[t] += x;
        __syncthreads();
    }
    if (t < nb) bs[t] = sh[t] - v;
    if (t == 255) *tot = sh[255];
}

__global__ void k_scan3_dual(int* __restrict__ off_src, int* __restrict__ off_mean,
                             const int* __restrict__ bsum, int n,
                             int* __restrict__ cur_src, int* __restrict__ cur_mean) {
    int i = blockIdx.x * 256 + threadIdx.x;
    if (i < n) {
        int v = off_src[i] + bsum[i >> 10];
        off_src[i] = v;
        cur_src[i] = v;
    } else if (i < 2 * n) {
        int j = i - n;
        int v = off_mean[j] + bsum[256 + (j >> 10)];
        off_mean[j] = v;
        cur_mean[j] = v;
    }
}

// ------- fused CSR slot fill: attn list + packed mean list -------
__global__ void k_fill_all(const int* __restrict__ er_src, const int* __restrict__ er_dst,
                           const int* __restrict__ ee_src, const int* __restrict__ ee_dst,
                           const int* __restrict__ rr_src, const int* __restrict__ rr_dst,
                           const float* __restrict__ ee_w,
                           int* __restrict__ cur_src, int* __restrict__ cur_mean,
                           int* __restrict__ er_lst, int2* __restrict__ gpack,
                           int E_ER, int E_EE, int E_RR) {
    int i = blockIdx.x * 256 + threadIdx.x;
    if (i < E_ER) {
        int p = atomicAdd(cur_src + er_src[i], 1);
        er_lst[p] = er_dst[i];
        return;
    }
    i -= E_ER;
    int gat, sct;
    float w;
    if (i < E_ER) {
        sct = er_dst[i]; gat = er_src[i]; w = 1.f;
    } else {
        i -= E_ER;
        if (i < E_EE) {
            sct = ee_src[i]; gat = ee_dst[i]; w = ee_w[i];
        } else {
            i -= E_EE;
            if (i >= E_RR) return;
            sct = rr_src[i]; gat = rr_dst[i]; w = 1.f;
        }
    }
    int p = atomicAdd(cur_mean + sct, 1);
    int2 pk;
    pk.x = gat;
    pk.y = __float_as_int(w);
    gpack[p] = pk;
}

// ---------------- casts ----------------
__global__ void k_cast4(const float* __restrict__ src, u16* __restrict__ dst, int n4) {
    int i = blockIdx.x * 256 + threadIdx.x;
    if (i >= n4) return;
    float4 v = ((const float4*)src)[i];
    ushort4 o;
    o.x = f2b(v.x); o.y = f2b(v.y); o.z = f2b(v.z); o.w = f2b(v.w);
    ((ushort4*)dst)[i] = o;
}

// fused weight casts: Wcat (256x128 gathered from Wattn 128x256) then W1,W2,W3
__global__ void k_cast_w(const float* __restrict__ Wattn,
                         const float* __restrict__ W1, const float* __restrict__ W2,
                         const float* __restrict__ W3,
                         u16* __restrict__ Wcat, u16* __restrict__ W123h) {
    int i = blockIdx.x * 256 + threadIdx.x;
    if (i < 32768) {
        int dd = i >> 7, k = i & 127;
        float v = (dd < 128) ? Wattn[(size_t)dd * 256 + k]
                             : Wattn[(size_t)(dd - 128) * 256 + 128 + k];
        Wcat[i] = f2b(v);
        return;
    }
    i -= 32768;
    if (i < 16384) { W123h[i] = f2b(W1[i]); return; }
    i -= 16384;
    if (i < 16384) { W123h[16384 + i] = f2b(W2[i]); return; }
    i -= 16384;
    if (i < 16384) W123h[32768 + i] = f2b(W3[i]);
}

// --- A = embh @ Wcat^T via MFMA. A[n][dd] bf16, dd in [0,256) ---
__global__ __launch_bounds__(256) void k_precompute_mfma(const u16* __restrict__ embh,
                                                         const u16* __restrict__ Wcat,
                                                         u16* __restrict__ A, int N) {
    __shared__ u16 sX[64][136];
    int nb = blockIdx.x * 64;
    int tid = threadIdx.x;
    for (int i = tid; i < 1024; i += 256) {
        int row = i >> 4, c8 = i & 15;
        int n = nb + row;
        uint4 v = make_uint4(0u, 0u, 0u, 0u);
        if (n < N) v = *(const uint4*)(embh + (size_t)n * 128 + c8 * 8);
        *(uint4*)&sX[row][c8 * 8] = v;
    }
    __syncthreads();
    int wid = tid >> 6, lane = tid & 63;
    int quad = lane >> 4, l15 = lane & 15;
#pragma unroll
    for (int ns = 0; ns < 4; ns++) {
        int dbase = (wid * 4 + ns) * 16;
        bf16x8 b[4];
#pragma unroll
        for (int ks = 0; ks < 4; ks++)
            b[ks] = *(const bf16x8*)(Wcat + (size_t)(dbase + l15) * 128 + ks * 32 + quad * 8);
#pragma unroll
        for (int ms = 0; ms < 4; ms++) {
            f32x4 acc = {0.f, 0.f, 0.f, 0.f};
#pragma unroll
            for (int ks = 0; ks < 4; ks++) {
                bf16x8 a = *(const bf16x8*)&sX[ms * 16 + l15][ks * 32 + quad * 8];
                acc = MFMA16x16(a, b[ks], acc);
            }
#pragma unroll
            for (int r = 0; r < 4; r++) {
                int row = nb + ms * 16 + quad * 4 + r;
                if (row < N) A[(size_t)row * 256 + dbase + l15] = f2b(acc[r]);
            }
        }
    }
}

// ------- fused attention: logits + softmax (no-max: |v|<=11.4, exp safe) -------
__global__ __launch_bounds__(256) void k_attn(const u16* __restrict__ A,
                                              const int* __restrict__ off,
                                              const int* __restrict__ lst,
                                              const u16* __restrict__ embh,
                                              const float* __restrict__ Wb,
                                              const float* __restrict__ w0w,
                                              const float* __restrict__ w0b,
                                              u16* __restrict__ attn_h, int N) {
    int node = blockIdx.x * 4 + (threadIdx.x >> 6);
    if (node >= N) return;
    int lane = threadIdx.x & 63;
    u32 ah = *(const u32*)(A + (size_t)node * 256 + 128 + 2 * lane);
    float ahx = b2f(ah), ahy = b2f(ah >> 16);
    float2 bb = *(const float2*)(Wb + 2 * lane);
    float2 ww = *(const float2*)(w0w + 2 * lane);
    float w0bias = w0b[0];
    int s0 = off[node], s1 = off[node + 1];
    float l = 0.f, ox = 0.f, oy = 0.f;
    int s = s0;
    for (; s + 2 <= s1; s += 2) {
        int d0 = lst[s], d1 = lst[s + 1];
        u32 ar0 = *(const u32*)(A + (size_t)d0 * 256 + 2 * lane);
        u32 ar1 = *(const u32*)(A + (size_t)d1 * 256 + 2 * lane);
        u32 ev0 = *(const u32*)(embh + (size_t)d0 * 128 + 2 * lane);
        u32 ev1 = *(const u32*)(embh + (size_t)d1 * 128 + 2 * lane);
        float p0 = tanh_fast(b2f(ar0) + ahx + bb.x) * ww.x +
                   tanh_fast(b2f(ar0 >> 16) + ahy + bb.y) * ww.y;
        float p1 = tanh_fast(b2f(ar1) + ahx + bb.x) * ww.x +
                   tanh_fast(b2f(ar1 >> 16) + ahy + bb.y) * ww.y;
#pragma unroll
        for (int o = 32; o; o >>= 1) {
            p0 += __shfl_xor(p0, o);
            p1 += __shfl_xor(p1, o);
        }
        float e0 = __expf(p0 + w0bias);
        float e1 = __expf(p1 + w0bias);
        l += e0 + e1;
        ox += e0 * b2f(ev0) + e1 * b2f(ev1);
        oy += e0 * b2f(ev0 >> 16) + e1 * b2f(ev1 >> 16);
    }
    if (s < s1) {
        int d0 = lst[s];
        u32 ar0 = *(const u32*)(A + (size_t)d0 * 256 + 2 * lane);
        u32 ev0 = *(const u32*)(embh + (size_t)d0 * 128 + 2 * lane);
        float p0 = tanh_fast(b2f(ar0) + ahx + bb.x) * ww.x +
                   tanh_fast(b2f(ar0 >> 16) + ahy + bb.y) * ww.y;
#pragma unroll
        for (int o = 32; o; o >>= 1) p0 += __shfl_xor(p0, o);
        float e0 = __expf(p0 + w0bias);
        l += e0;
        ox += e0 * b2f(ev0);
        oy += e0 * b2f(ev0 >> 16);
    }
    float inv = 1.f / (l + 1e-9f);
    u32 o = (u32)f2b(ox * inv) | ((u32)f2b(oy * inv) << 16);
    *(u32*)(attn_h + (size_t)node * 128 + 2 * lane) = o;
}

// ---------------- unified mean gather: 1 wave/node, 4 edges in flight ----------------
__global__ __launch_bounds__(256) void k_mean_g(const int* __restrict__ off,
                                                const int2* __restrict__ gpack,
                                                const u16* __restrict__ embh,
                                                u16* __restrict__ mean_h, int N) {
    int node = blockIdx.x * 4 + (threadIdx.x >> 6);
    if (node >= N) return;
    int lane = threadIdx.x & 63;
    int s0 = off[node], s1 = off[node + 1];
    float ax = 0.f, ay = 0.f, c = 0.f;
    int s = s0;
    for (; s + 4 <= s1; s += 4) {
        int2 p0 = gpack[s], p1 = gpack[s + 1], p2 = gpack[s + 2], p3 = gpack[s + 3];
        u32 v0 = *(const u32*)(embh + (size_t)p0.x * 128 + 2 * lane);
        u32 v1 = *(const u32*)(embh + (size_t)p1.x * 128 + 2 * lane);
        u32 v2 = *(const u32*)(embh + (size_t)p2.x * 128 + 2 * lane);
        u32 v3 = *(const u32*)(embh + (size_t)p3.x * 128 + 2 * lane);
        float w0 = __int_as_float(p0.y), w1 = __int_as_float(p1.y);
        float w2 = __int_as_float(p2.y), w3 = __int_as_float(p3.y);
        ax += w0 * b2f(v0) + w1 * b2f(v1) + w2 * b2f(v2) + w3 * b2f(v3);
        ay += w0 * b2f(v0 >> 16) + w1 * b2f(v1 >> 16) + w2 * b2f(v2 >> 16) + w3 * b2f(v3 >> 16);
        c += w0 + w1 + w2 + w3;
    }
    for (; s < s1; ++s) {
        int2 p0 = gpack[s];
        u32 v0 = *(const u32*)(embh + (size_t)p0.x * 128 + 2 * lane);
        float w0 = __int_as_float(p0.y);
        ax += w0 * b2f(v0);
        ay += w0 * b2f(v0 >> 16);
        c += w0;
    }
    c = c > 1.f ? c : 1.f;
    float inv = 1.f / c;
    u32 o = (u32)f2b(ax * inv) | ((u32)f2b(ay * inv) << 16);
    *(u32*)(mean_h + (size_t)node * 128 + 2 * lane) = o;
}

// --------- fused epilogue via MFMA: out = sum of 3 tanh(GEMM + bias) ---------
__global__ __launch_bounds__(256) void k_final_mfma(const u16* __restrict__ embh,
                                                    const u16* __restrict__ attn_h,
                                                    const u16* __restrict__ mean_h,
                                                    const u16* __restrict__ W123h,
                                                    const float* __restrict__ b1,
                                                    const float* __restrict__ b2,
                                                    const float* __restrict__ b3,
                                                    float* __restrict__ out, int N) {
    __shared__ u16 sX[3][64][136];
    int nb = blockIdx.x * 64;
    int tid = threadIdx.x;
    const u16* srcs[3] = {embh, attn_h, mean_h};
#pragma unroll
    for (int arr = 0; arr < 3; arr++) {
        const u16* s = srcs[arr];
        for (int i = tid; i < 1024; i += 256) {
            int row = i >> 4, c8 = i & 15;
            int n = nb + row;
            uint4 v = make_uint4(0u, 0u, 0u, 0u);
            if (n < N) v = *(const uint4*)(s + (size_t)n * 128 + c8 * 8);
            *(uint4*)&sX[arr][row][c8 * 8] = v;
        }
    }
    __syncthreads();
    int wid = tid >> 6, lane = tid & 63;
    int quad = lane >> 4, l15 = lane & 15;
#pragma unroll
    for (int ns = 0; ns < 2; ns++) {
        int dbase = (wid * 2 + ns) * 16;
        int d = dbase + l15;
        bf16x8 b[3][4];
#pragma unroll
        for (int arr = 0; arr < 3; arr++)
#pragma unroll
            for (int ks = 0; ks < 4; ks++)
                b[arr][ks] = *(const bf16x8*)(W123h + (size_t)arr * 16384 +
                                              (size_t)d * 128 + ks * 32 + quad * 8);
        float bias0 = b1[d], bias1 = b2[d], bias2 = b3[d];
#pragma unroll
        for (int ms = 0; ms < 4; ms++) {
            f32x4 acc0 = {0.f, 0.f, 0.f, 0.f};
            f32x4 acc1 = {0.f, 0.f, 0.f, 0.f};
            f32x4 acc2 = {0.f, 0.f, 0.f, 0.f};
#pragma unroll
            for (int ks = 0; ks < 4; ks++) {
                bf16x8 a0 = *(const bf16x8*)&sX[0][ms * 16 + l15][ks * 32 + quad * 8];
                bf16x8 a1 = *(const bf16x8*)&sX[1][ms * 16 + l15][ks * 32 + quad * 8];
                bf16x8 a2 = *(const bf16x8*)&sX[2][ms * 16 + l15][ks * 32 + quad * 8];
                acc0 = MFMA16x16(a0, b[0][ks], acc0);
                acc1 = MFMA16x16(a1, b[1][ks], acc1);
                acc2 = MFMA16x16(a2, b[2][ks], acc2);
            }
#pragma unroll
            for (int r = 0; r < 4; r++) {
                int row = nb + ms * 16 + quad * 4 + r;
                if (row < N)
                    out[(size_t)row * 128 + d] = tanh_fast(acc0[r] + bias0) +
                                                 tanh_fast(acc1[r] + bias1) +
                                                 tanh_fast(acc2[r] + bias2);
            }
        }
    }
}

extern "C" void kernel_launch(void* const* d_in, const int* in_sizes, int n_in,
                              void* d_out, int out_size, void* d_ws, size_t ws_size,
                              hipStream_t stream) {
    const float* emb     = (const float*)d_in[0];
    const int*   er_src  = (const int*)d_in[1];
    const int*   er_dst  = (const int*)d_in[2];
    const int*   ee_src  = (const int*)d_in[3];
    const int*   ee_dst  = (const int*)d_in[4];
    const float* ee_w    = (const float*)d_in[5];
    const int*   rr_src  = (const int*)d_in[6];
    const int*   rr_dst  = (const int*)d_in[7];
    const float* Wattn   = (const float*)d_in[8];
    const float* Wattn_b = (const float*)d_in[9];
    const float* w0w     = (const float*)d_in[10];
    const float* w0b     = (const float*)d_in[11];
    const float* W1      = (const float*)d_in[12];
    const float* b1      = (const float*)d_in[13];
    const float* W2      = (const float*)d_in[14];
    const float* b2      = (const float*)d_in[15];
    const float* W3      = (const float*)d_in[16];
    const float* b3      = (const float*)d_in[17];
    float* out = (float*)d_out;

    int N    = in_sizes[0] / D;
    int E_ER = in_sizes[1];
    int E_EE = in_sizes[3];
    int E_RR = in_sizes[6];
    int E_M  = E_ER + E_EE + E_RR;
    int E_T  = E_ER + E_M;  // hist/fill fused range

    char* ws = (char*)d_ws;
    size_t off_b = 0;
    auto alloc = [&](size_t bytes) -> void* {
        void* p = ws + off_b;
        off_b += (bytes + 255) & ~(size_t)255;
        return p;
    };
    // A (N x 256 bf16) dead after k_attn; mean_h aliases it.  ~128 MB total.
    u16*   embh   = (u16*)alloc((size_t)N * 128 * 2);
    u16*   A      = (u16*)alloc((size_t)N * 256 * 2);
    u16*   mean_h = A;
    u16*   attn_h = (u16*)alloc((size_t)N * 128 * 2);
    u16*   Wcat_h = (u16*)alloc(256 * 128 * 2);
    u16*   W123h  = (u16*)alloc(3 * 128 * 128 * 2);
    int*   cnt2     = (int*)alloc((size_t)2 * N * 4);  // [cnt_src | cnt_mean]
    int*   off_src  = (int*)alloc((size_t)(N + 1) * 4);
    int*   off_mean = (int*)alloc((size_t)(N + 1) * 4);
    int*   cur_src  = (int*)alloc((size_t)N * 4);
    int*   cur_mean = (int*)alloc((size_t)N * 4);
    int*   bsum     = (int*)alloc(512 * 4);  // [bsumA | bsumB]
    int*   er_lst   = (int*)alloc((size_t)E_ER * 4);
    int2*  gpack    = (int2*)alloc((size_t)E_M * 8);

    int nb_scan = (N + 1023) / 1024;  // must be <= 256

    // --- CSR build ---
    k_zero<<<(2 * N + 255) / 256, 256, 0, stream>>>(cnt2, 2 * N);
    k_hist_all<<<(E_T + 255) / 256, 256, 0, stream>>>(er_src, er_dst, ee_src, rr_src,
                                                      cnt2, cnt2 + N, E_ER, E_EE, E_RR);
    k_scan1_dual<<<2 * nb_scan, 256, 0, stream>>>(cnt2, N, off_src, off_mean, bsum, nb_scan);
    k_scan2_dual<<<2, 256, 0, stream>>>(bsum, nb_scan, off_src + N, off_mean + N);
    k_scan3_dual<<<(2 * N + 255) / 256, 256, 0, stream>>>(off_src, off_mean, bsum, N,
                                                          cur_src, cur_mean);
    k_fill_all<<<(E_T + 255) / 256, 256, 0, stream>>>(er_src, er_dst, ee_src, ee_dst,
                                                      rr_src, rr_dst, ee_w,
                                                      cur_src, cur_mean, er_lst, gpack,
                                                      E_ER, E_EE, E_RR);

    // --- casts ---
    k_cast4<<<((N * 128 / 4) + 255) / 256, 256, 0, stream>>>(emb, embh, N * 128 / 4);
    k_cast_w<<<(81920 + 255) / 256, 256, 0, stream>>>(Wattn, W1, W2, W3, Wcat_h, W123h);

    // --- compute ---
    k_precompute_mfma<<<(N + 63) / 64, 256, 0, stream>>>(embh, Wcat_h, A, N);
    k_attn<<<(N + 3) / 4, 256, 0, stream>>>(A, off_src, er_lst, embh, Wattn_b, w0w, w0b,
                                            attn_h, N);
    // A dead; its space becomes mean_h
    k_mean_g<<<(N + 3) / 4, 256, 0, stream>>>(off_mean, gpack, embh, mean_h, N);
    k_final_mfma<<<(N + 63) / 64, 256, 0, stream>>>(embh, attn_h, mean_h, W123h,
                                                    b1, b2, b3, out, N);
}